// Round 1
// baseline (741.563 us; speedup 1.0000x reference)
//
#include <hip/hip_runtime.h>

// Problem constants (from reference): B=1, C=32, N_IN=1e6, N_OUT=4e6, fp32.
// C is hardcoded to 32; N_IN/N_OUT derived from in_sizes.

#define CH 32

// Kernel 1: transpose in[C][N_IN] -> in_t[N_IN][C].
// Reads coalesced per channel; each thread owns one input position i and
// writes its 32-channel vector as 8 contiguous float4 (128 B per thread).
__global__ __launch_bounds__(256) void UpSampleConst_transpose(
    const float* __restrict__ in, float* __restrict__ in_t, int n_in) {
    int i = blockIdx.x * blockDim.x + threadIdx.x;
    if (i >= n_in) return;
    float v[CH];
#pragma unroll
    for (int c = 0; c < CH; ++c) {
        v[c] = in[(size_t)c * n_in + i];   // lane-coalesced per c
    }
    float4* dst = reinterpret_cast<float4*>(in_t + (size_t)i * CH);
#pragma unroll
    for (int k = 0; k < CH / 4; ++k) {
        dst[k] = make_float4(v[4 * k + 0], v[4 * k + 1], v[4 * k + 2], v[4 * k + 3]);
    }
}

// Kernel 2: gather. Each thread owns one output particle j:
// reads parent vector (128 B contiguous, float4 x8, random but fully-used
// sectors), then writes one float per channel (lane-coalesced 256 B/wave
// per store instruction).
__global__ __launch_bounds__(256) void UpSampleConst_gather(
    const float* __restrict__ in_t, const int* __restrict__ idx,
    float* __restrict__ out, int n_out) {
    int j = blockIdx.x * blockDim.x + threadIdx.x;
    if (j >= n_out) return;
    int p = idx[j];
    const float4* src = reinterpret_cast<const float4*>(in_t + (size_t)p * CH);
    float4 v[CH / 4];
#pragma unroll
    for (int k = 0; k < CH / 4; ++k) v[k] = src[k];   // 8 independent loads (MLP)
    const float* vf = reinterpret_cast<const float*>(v);
#pragma unroll
    for (int c = 0; c < CH; ++c) {
        out[(size_t)c * n_out + j] = vf[c];
    }
}

// Fallback if workspace can't hold the transposed copy: direct gather
// (scattered 4 B reads). Same math, worse locality.
__global__ __launch_bounds__(256) void UpSampleConst_direct(
    const float* __restrict__ in, const int* __restrict__ idx,
    float* __restrict__ out, int n_in, int n_out) {
    int j = blockIdx.x * blockDim.x + threadIdx.x;
    if (j >= n_out) return;
    int p = idx[j];
#pragma unroll
    for (int c = 0; c < CH; ++c) {
        out[(size_t)c * n_out + j] = in[(size_t)c * n_in + p];
    }
}

extern "C" void kernel_launch(void* const* d_in, const int* in_sizes, int n_in_args,
                              void* d_out, int out_size, void* d_ws, size_t ws_size,
                              hipStream_t stream) {
    const float* in  = (const float*)d_in[0];   // [1, 32, N_IN] fp32
    const int*   idx = (const int*)d_in[1];     // [N_OUT] int32
    float*       out = (float*)d_out;           // [1, 32, N_OUT] fp32

    const int n_in  = in_sizes[0] / CH;
    const int n_out = in_sizes[1];

    const size_t need = (size_t)n_in * CH * sizeof(float);
    if (ws_size >= need) {
        float* in_t = (float*)d_ws;
        dim3 blk(256);
        dim3 grid_t((n_in + 255) / 256);
        UpSampleConst_transpose<<<grid_t, blk, 0, stream>>>(in, in_t, n_in);
        dim3 grid_g((n_out + 255) / 256);
        UpSampleConst_gather<<<grid_g, blk, 0, stream>>>(in_t, idx, out, n_out);
    } else {
        dim3 blk(256);
        dim3 grid_g((n_out + 255) / 256);
        UpSampleConst_direct<<<grid_g, blk, 0, stream>>>(in, idx, out, n_in, n_out);
    }
}